// Round 15
// baseline (113.873 us; speedup 1.0000x reference)
//
#include <hip/hip_runtime.h>
#include <math.h>

// N=8192 rows, D=256, fp32 in, scalar fp32 out.
// out = mean_i ||v0_i-v1_i|| + 0.5*(mean_i log S0_i + mean_i log S1_i) - log(N-1)
// S_i = sum_{j!=i} exp(-sqrt(max(sq_i+sq_j-2*z_i.z_j,0)))
//
// Round 15 = r14 with 4-tile row segments (was 2). Each block stages the 32KB
// i8 A panel once and sweeps up to 4 B tiles of its bi row; row sums stay in
// registers across all tiles -> one LDS transpose + one row-atomic set per
// block. 1088 blocks (was 2112): per-block fixed costs (staging stall,
// transpose, atomics) halved again. K-loop and epilogue math unchanged
// (protected: i8 MFMA barrier-free loop, no-fmax, diag-specialized).

#define D_DIM 256
#define NB 64                 // 8192/128 panels
#define NSEG 544              // sum over rows bi of ceil((64-bi)/4)
#define S_Q 26.0f             // i8 quant scale
#define LOG2E2 2.0813689810f  // (log2 e)^2
#define LP 65                 // padded LDS pitch in float4 (prep)

typedef int i32x4 __attribute__((ext_vector_type(4)));
typedef unsigned int u32;
#define AS1 __attribute__((address_space(1)))
#define AS3 __attribute__((address_space(3)))

__device__ inline void load_lds16(const void* g, void* l) {
  __builtin_amdgcn_global_load_lds((const AS1 u32*)g, (AS3 u32*)l, 16, 0, 0);
}

__device__ inline int q8(float x) {
  return __float2int_rn(fminf(fmaxf(x * S_Q, -127.0f), 127.0f));
}
__device__ inline u32 q8x4(const float4 f) {
  return (u32)(q8(f.x) & 255) | ((u32)(q8(f.y) & 255) << 8) |
         ((u32)(q8(f.z) & 255) << 16) | ((u32)(q8(f.w) & 255) << 24);
}

// G4(M) = sum_{L=1..M} ceil(L/4) (segment-count prefix helper).
__device__ inline int G4(int M) {
  const int a = M >> 2, b = M & 3;
  return 2 * a * (a + 1) + b * (a + 1);
}

// One block per 16-row tile R. Stages both views' rows in LDS (padded pitch),
// emits packed fragment-ordered i8 planes, computes prescaled sq norms +
// align parts, zeroes S.
// Plane layout: 16B chunk index (R*4 + s)*64 + q*16 + rr holds elements
// (row = R*16 + rr, k = s*64 + q*16 + j), j=0..15 -- one lane-operand of
// mfma_i32_16x16x64_i8 per chunk; one wave-fragment per 1KB block.
__global__ __launch_bounds__(256) void prep(
    const float* __restrict__ v0, const float* __restrict__ v1,
    unsigned char* __restrict__ ph0, unsigned char* __restrict__ ph1,
    float* __restrict__ sq0, float* __restrict__ sq1,
    float* __restrict__ S0, float* __restrict__ S1,
    float* __restrict__ align_part) {
  __shared__ float4 l0[16 * LP], l1[16 * LP];   // 16 rows, padded pitch
  __shared__ float red0[4][16], red1[4][16], red2[4][16];
  const int R = blockIdx.x;
  const int t = threadIdx.x;

  // coalesced load: 16 rows x 64 float4 per view (stored at padded pitch)
  #pragma unroll
  for (int p = 0; p < 4; ++p) {
    const int slot = t + p * 256;
    const int r = slot >> 6, col = slot & 63;
    const size_t g = (size_t)(R * 16 + r) * 64 + col;
    l0[r * LP + col] = ((const float4*)v0)[g];
    l1[r * LP + col] = ((const float4*)v1)[g];
  }
  __syncthreads();

  // quant+pack: thread t -> row rr = t&15, k-group c = t>>4 (16 elements)
  {
    const int rr = t & 15, c = t >> 4;
    const int s = c >> 2, q = c & 3;
    const int li = rr * LP + c * 4;       // float4 index of k = c*16
    uint4 u0, u1;
    u0.x = q8x4(l0[li + 0]); u0.y = q8x4(l0[li + 1]);
    u0.z = q8x4(l0[li + 2]); u0.w = q8x4(l0[li + 3]);
    u1.x = q8x4(l1[li + 0]); u1.y = q8x4(l1[li + 1]);
    u1.z = q8x4(l1[li + 2]); u1.w = q8x4(l1[li + 3]);
    const size_t dst = (size_t)(R * 4 + s) * 64 + q * 16 + rr;
    ((uint4*)ph0)[dst] = u0;
    ((uint4*)ph1)[dst] = u1;
  }

  // norms: thread t sums 16 elements of row (t&15), segment (t>>4)
  {
    const int rr = t & 15;
    const int base = rr * LP + (t >> 4) * 4;
    float s0p = 0.f, s1p = 0.f, s2p = 0.f;
    #pragma unroll
    for (int c = 0; c < 4; ++c) {
      const float4 a = l0[base + c], b = l1[base + c];
      s0p += a.x * a.x + a.y * a.y + a.z * a.z + a.w * a.w;
      s1p += b.x * b.x + b.y * b.y + b.z * b.z + b.w * b.w;
      const float dx = a.x - b.x, dy = a.y - b.y, dz = a.z - b.z, dw = a.w - b.w;
      s2p += dx * dx + dy * dy + dz * dz + dw * dw;
    }
    s0p += __shfl_xor(s0p, 16, 64); s0p += __shfl_xor(s0p, 32, 64);
    s1p += __shfl_xor(s1p, 16, 64); s1p += __shfl_xor(s1p, 32, 64);
    s2p += __shfl_xor(s2p, 16, 64); s2p += __shfl_xor(s2p, 32, 64);
    const int w = t >> 6, lane = t & 63;
    if (lane < 16) { red0[w][lane] = s0p; red1[w][lane] = s1p; red2[w][lane] = s2p; }
  }
  __syncthreads();
  if (t < 16) {
    const int row = R * 16 + t;
    const float a0 = red0[0][t] + red0[1][t] + red0[2][t] + red0[3][t];
    const float a1 = red1[0][t] + red1[1][t] + red1[2][t] + red1[3][t];
    const float a2 = red2[0][t] + red2[1][t] + red2[2][t] + red2[3][t];
    sq0[row] = a0 * LOG2E2;               // prescaled: epilogue works in log2 units
    sq1[row] = a1 * LOG2E2;
    align_part[row] = sqrtf(a2);
    S0[row] = 0.0f;
    S1[row] = 0.0f;
  }
}

// Persistent 4-tile row segments; grid (NSEG, 2=view). 4 waves in 2x2, each
// wave 4x4 tiles of mfma_i32_16x16x64_i8 over 4 K=64 chunks per tile. A panel
// staged once; B fragments stream global->VGPR with 1-chunk prefetch. No
// barriers inside or between tiles.
__global__ __launch_bounds__(256) void entropy_tile(
    const unsigned char* __restrict__ ph0, const unsigned char* __restrict__ ph1,
    const float* __restrict__ sq0, const float* __restrict__ sq1,
    float* __restrict__ S0, float* __restrict__ S1) {
  const unsigned char* __restrict__ ph = blockIdx.y ? ph1 : ph0;
  const float* __restrict__ sq = blockIdx.y ? sq1 : sq0;
  float* __restrict__ S        = blockIdx.y ? S1 : S0;

  // decode segment -> (bi, q): row bi has ceil((64-bi)/4) segments;
  // prefix P(bi) = NSEG - G4(64-bi).
  const int lin = blockIdx.x;
  int bi = 0;
  while (NSEG - G4(64 - (bi + 1)) <= lin) ++bi;
  const int q = lin - (NSEG - G4(64 - bi));
  const int bj0 = bi + 4 * q;

  // 32 KB: the A panel (i8, fragment order). Front 17408 B reused as epilogue
  // scratch (guarded by the post-tiles barrier).
  __shared__ __align__(16) char smem[32768];
  float* swp = (float*)smem;

  const int t = threadIdx.x, lane = t & 63, w = t >> 6;
  const int wi = w >> 1, wj = w & 1;
  const int quad = lane >> 4, l15 = lane & 15;
  const int i0 = bi * 128;

  // One-shot A panel stage: 32 x 1KB segments, 8 per wave.
  #pragma unroll
  for (int r8 = 0; r8 < 8; ++r8) {
    const int seg = w * 8 + r8;
    const unsigned char* src = ph + (size_t)bi * 32768 + seg * 1024 + lane * 16;
    load_lds16(src, smem + seg * 1024);
  }
  __syncthreads();   // drains A staging

  const i32x4* __restrict__ phv = (const i32x4*)ph;
  const i32x4* smemv = (const i32x4*)smem;
  const float K2 = 2.0f * LOG2E2 / (S_Q * S_Q);

  float prow[4][4];   // row partial sums, accumulated across all tiles
  #pragma unroll
  for (int m = 0; m < 4; ++m)
    #pragma unroll
    for (int r = 0; r < 4; ++r) prow[m][r] = 0.f;

  auto do_tile = [&](const int bj, const bool diag_t) {
    const int j0 = bj * 128;
    const int baseB = ((bj * 8 + wj * 4) * 4) * 64 + lane;

    float sjl[4];
    #pragma unroll
    for (int n = 0; n < 4; ++n) sjl[n] = sq[j0 + wj * 64 + n * 16 + l15];

    i32x4 bF[2][4];
    #pragma unroll
    for (int n = 0; n < 4; ++n) bF[0][n] = phv[baseB + (n * 4) * 64];

    i32x4 acc[4][4];
    #pragma unroll
    for (int m = 0; m < 4; ++m)
      #pragma unroll
      for (int n = 0; n < 4; ++n) acc[m][n] = (i32x4){0, 0, 0, 0};

    #pragma unroll
    for (int s = 0; s < 4; ++s) {
      const int cur = s & 1, nxt = cur ^ 1;
      if (s < 3) {
        #pragma unroll
        for (int n = 0; n < 4; ++n)
          bF[nxt][n] = phv[baseB + (n * 4 + s + 1) * 64];
      }
      i32x4 ah[4];
      #pragma unroll
      for (int m = 0; m < 4; ++m)
        ah[m] = smemv[(size_t)((wi * 4 + m) * 4 + s) * 64 + lane];
      #pragma unroll
      for (int m = 0; m < 4; ++m)
        #pragma unroll
        for (int n = 0; n < 4; ++n)
          acc[m][n] = __builtin_amdgcn_mfma_i32_16x16x64_i8(ah[m], bF[cur][n], acc[m][n], 0, 0, 0);
      // no barrier: A panel read-only, B private
    }

    // epilogue-lite: accumulate into prow (registers) + per-tile column sums.
    // C/D layout: col = l15, row = quad*4+reg. No fmax (off-diag d2 >= ~260;
    // diag NaN masked after exp).
    float csum[4] = {0.f, 0.f, 0.f, 0.f};
    #pragma unroll
    for (int m = 0; m < 4; ++m) {
      #pragma unroll
      for (int r = 0; r < 4; ++r) {
        const int rowl = m * 16 + quad * 4 + r;
        const int gi = i0 + wi * 64 + rowl;
        const float si = sq[gi];
        float p = 0.f;
        #pragma unroll
        for (int n = 0; n < 4; ++n) {
          const float d2 = fmaf(-K2, (float)acc[m][n][r], si + sjl[n]);
          float e = __builtin_amdgcn_exp2f(-__builtin_amdgcn_sqrtf(d2));
          if (diag_t && gi == j0 + wj * 64 + n * 16 + l15) e = 0.f;  // diag mask
          p += e;
          csum[n] += e;
        }
        prow[m][r] += p;
      }
    }
    if (!diag_t) {
      // column sums -> symmetric contribution S[j] += sum_i exp(-d_ij)
      #pragma unroll
      for (int n = 0; n < 4; ++n) {
        float c2 = csum[n];
        c2 += __shfl_xor(c2, 16, 64);
        c2 += __shfl_xor(c2, 32, 64);
        if (quad == 0) atomicAdd(&S[j0 + wj * 64 + n * 16 + l15], c2);
      }
    }
  };

  if (bj0 == bi) do_tile(bi, true); else do_tile(bj0, false);
  if (bj0 + 1 < NB) do_tile(bj0 + 1, false);
  if (bj0 + 2 < NB) do_tile(bj0 + 2, false);
  if (bj0 + 3 < NB) do_tile(bj0 + 3, false);

  __syncthreads();   // all waves done reading A before scratch reuse

  // Row reduction: LDS transpose of prow, one atomic set per block.
  const int wbase = w * 1088;  // 64 rows x 17 floats per wave
  #pragma unroll
  for (int m = 0; m < 4; ++m)
    #pragma unroll
    for (int r = 0; r < 4; ++r)
      swp[wbase + (m * 16 + quad * 4 + r) * 17 + l15] = prow[m][r];
  float rs = 0.f;
  #pragma unroll
  for (int j = 0; j < 16; ++j) rs += swp[wbase + lane * 17 + j];
  atomicAdd(&S[i0 + wi * 64 + lane], rs);
}

// Stage 1: 32 blocks x 256 threads, one row each; per-block partials.
__global__ __launch_bounds__(256) void finalize_part(
    const float* __restrict__ S0, const float* __restrict__ S1,
    const float* __restrict__ align_part,
    float* __restrict__ part_log, float* __restrict__ part_align) {
  __shared__ float shl[4], sha[4];
  const int t = threadIdx.x, lane = t & 63, w = t >> 6;
  const int idx = blockIdx.x * 256 + t;
  float lg = __logf(S0[idx]) + __logf(S1[idx]);
  float al = align_part[idx];
  #pragma unroll
  for (int o = 1; o < 64; o <<= 1) {
    lg += __shfl_xor(lg, o, 64);
    al += __shfl_xor(al, o, 64);
  }
  if (lane == 0) { shl[w] = lg; sha[w] = al; }
  __syncthreads();
  if (t == 0) {
    part_log[blockIdx.x] = shl[0] + shl[1] + shl[2] + shl[3];
    part_align[blockIdx.x] = sha[0] + sha[1] + sha[2] + sha[3];
  }
}

// Stage 2: one wave combines 32 partials.
__global__ void finalize_final(const float* __restrict__ part_log,
                               const float* __restrict__ part_align,
                               float* __restrict__ out, int n) {
  const int lane = threadIdx.x & 63;
  double lg = (lane < 32) ? (double)part_log[lane] : 0.0;
  double al = (lane < 32) ? (double)part_align[lane] : 0.0;
  #pragma unroll
  for (int o = 1; o < 32; o <<= 1) {
    lg += __shfl_xor(lg, o, 64);
    al += __shfl_xor(al, o, 64);
  }
  if (lane == 0) {
    double align = al / (double)n;
    double entropy = 0.5 * lg / (double)n - log((double)(n - 1));
    out[0] = (float)(align + entropy);
  }
}

extern "C" void kernel_launch(void* const* d_in, const int* in_sizes, int n_in,
                              void* d_out, int out_size, void* d_ws, size_t ws_size,
                              hipStream_t stream) {
  const float* v0 = (const float*)d_in[0];
  const float* v1 = (const float*)d_in[1];
  float* out = (float*)d_out;
  const int n = in_sizes[0] / D_DIM;  // 8192

  float* ws         = (float*)d_ws;
  float* sq0        = ws;             // n f32 (prescaled by log2e^2)
  float* sq1        = ws + n;
  float* S0         = ws + 2 * n;
  float* S1         = ws + 3 * n;
  float* align_part = ws + 4 * n;
  float* part_log   = ws + 5 * n;     // 32 f32
  float* part_align = ws + 5 * n + 32;
  // packed i8 planes, 16B-aligned (5n+64 floats from base)
  unsigned char* ph0 = (unsigned char*)(ws + 5 * n + 64);  // n*256 i8 = 2 MB
  unsigned char* ph1 = ph0 + (size_t)n * D_DIM;            // 2 MB

  prep<<<n / 16, 256, 0, stream>>>(v0, v1, ph0, ph1, sq0, sq1, S0, S1, align_part);

  dim3 grid(NSEG, 2);
  entropy_tile<<<grid, 256, 0, stream>>>(ph0, ph1, sq0, sq1, S0, S1);

  finalize_part<<<n / 256, 256, 0, stream>>>(S0, S1, align_part, part_log, part_align);
  finalize_final<<<1, 64, 0, stream>>>(part_log, part_align, out, n);
}

// Round 16
// 113.354 us; speedup vs baseline: 1.0046x; 1.0046x over previous
//
#include <hip/hip_runtime.h>
#include <math.h>

// N=8192 rows, D=256, fp32 in, scalar fp32 out.
// out = mean_i ||v0_i-v1_i|| + 0.5*(mean_i log S0_i + mean_i log S1_i) - log(N-1)
// S_i = sum_{j!=i} exp(-sqrt(max(sq_i+sq_j-2*z_i.z_j,0)))
//
// Round 16 = r14 (best verified: entropy 48.0us, 2-tile persistent segments)
// + single ticketed finalize (3 dispatches total). r15's 4-tile segments
// regressed (under-subscription); reverted. The finalize ticket lives in a
// 32-block kernel (not the 4160-block entropy kernel -- that was r9's
// mistake): fp32 atomic accumulators at the L2 coherence point, returning
// atomicAdd(+0.0f) read by the last block, no device fence anywhere.

#define D_DIM 256
#define NB 64                 // 8192/128 panels
#define NSEG 1056             // sum over rows bi of ceil((64-bi)/2)
#define S_Q 26.0f             // i8 quant scale
#define LOG2E2 2.0813689810f  // (log2 e)^2
#define LP 65                 // padded LDS pitch in float4 (prep)

typedef int i32x4 __attribute__((ext_vector_type(4)));
typedef unsigned int u32;
#define AS1 __attribute__((address_space(1)))
#define AS3 __attribute__((address_space(3)))

__device__ inline void load_lds16(const void* g, void* l) {
  __builtin_amdgcn_global_load_lds((const AS1 u32*)g, (AS3 u32*)l, 16, 0, 0);
}

__device__ inline int q8(float x) {
  return __float2int_rn(fminf(fmaxf(x * S_Q, -127.0f), 127.0f));
}
__device__ inline u32 q8x4(const float4 f) {
  return (u32)(q8(f.x) & 255) | ((u32)(q8(f.y) & 255) << 8) |
         ((u32)(q8(f.z) & 255) << 16) | ((u32)(q8(f.w) & 255) << 24);
}

// G(M) = sum_{L=1..M} ceil(L/2); segment-count prefix helper.
__device__ inline int Gfun(int M) {
  const int m = M >> 1;
  return (M & 1) ? (m + 1) * (m + 1) : m * (m + 1);
}

// One block per 16-row tile R. Stages both views' rows in LDS (padded pitch),
// emits packed fragment-ordered i8 planes, computes prescaled sq norms +
// align parts, zeroes S and the finalize accumulators/ticket.
// Plane layout: 16B chunk index (R*4 + s)*64 + q*16 + rr holds elements
// (row = R*16 + rr, k = s*64 + q*16 + j), j=0..15 -- one lane-operand of
// mfma_i32_16x16x64_i8 per chunk; one wave-fragment per 1KB block.
__global__ __launch_bounds__(256) void prep(
    const float* __restrict__ v0, const float* __restrict__ v1,
    unsigned char* __restrict__ ph0, unsigned char* __restrict__ ph1,
    float* __restrict__ sq0, float* __restrict__ sq1,
    float* __restrict__ S0, float* __restrict__ S1,
    float* __restrict__ align_part,
    float* __restrict__ acc, int* __restrict__ cnt) {
  __shared__ float4 l0[16 * LP], l1[16 * LP];   // 16 rows, padded pitch
  __shared__ float red0[4][16], red1[4][16], red2[4][16];
  const int R = blockIdx.x;
  const int t = threadIdx.x;

  if (R == 0 && t == 0) { acc[0] = 0.0f; acc[1] = 0.0f; *cnt = 0; }

  // coalesced load: 16 rows x 64 float4 per view (stored at padded pitch)
  #pragma unroll
  for (int p = 0; p < 4; ++p) {
    const int slot = t + p * 256;
    const int r = slot >> 6, col = slot & 63;
    const size_t g = (size_t)(R * 16 + r) * 64 + col;
    l0[r * LP + col] = ((const float4*)v0)[g];
    l1[r * LP + col] = ((const float4*)v1)[g];
  }
  __syncthreads();

  // quant+pack: thread t -> row rr = t&15, k-group c = t>>4 (16 elements)
  {
    const int rr = t & 15, c = t >> 4;
    const int s = c >> 2, q = c & 3;
    const int li = rr * LP + c * 4;       // float4 index of k = c*16
    uint4 u0, u1;
    u0.x = q8x4(l0[li + 0]); u0.y = q8x4(l0[li + 1]);
    u0.z = q8x4(l0[li + 2]); u0.w = q8x4(l0[li + 3]);
    u1.x = q8x4(l1[li + 0]); u1.y = q8x4(l1[li + 1]);
    u1.z = q8x4(l1[li + 2]); u1.w = q8x4(l1[li + 3]);
    const size_t dst = (size_t)(R * 4 + s) * 64 + q * 16 + rr;
    ((uint4*)ph0)[dst] = u0;
    ((uint4*)ph1)[dst] = u1;
  }

  // norms: thread t sums 16 elements of row (t&15), segment (t>>4)
  {
    const int rr = t & 15;
    const int base = rr * LP + (t >> 4) * 4;
    float s0p = 0.f, s1p = 0.f, s2p = 0.f;
    #pragma unroll
    for (int c = 0; c < 4; ++c) {
      const float4 a = l0[base + c], b = l1[base + c];
      s0p += a.x * a.x + a.y * a.y + a.z * a.z + a.w * a.w;
      s1p += b.x * b.x + b.y * b.y + b.z * b.z + b.w * b.w;
      const float dx = a.x - b.x, dy = a.y - b.y, dz = a.z - b.z, dw = a.w - b.w;
      s2p += dx * dx + dy * dy + dz * dz + dw * dw;
    }
    s0p += __shfl_xor(s0p, 16, 64); s0p += __shfl_xor(s0p, 32, 64);
    s1p += __shfl_xor(s1p, 16, 64); s1p += __shfl_xor(s1p, 32, 64);
    s2p += __shfl_xor(s2p, 16, 64); s2p += __shfl_xor(s2p, 32, 64);
    const int w = t >> 6, lane = t & 63;
    if (lane < 16) { red0[w][lane] = s0p; red1[w][lane] = s1p; red2[w][lane] = s2p; }
  }
  __syncthreads();
  if (t < 16) {
    const int row = R * 16 + t;
    const float a0 = red0[0][t] + red0[1][t] + red0[2][t] + red0[3][t];
    const float a1 = red1[0][t] + red1[1][t] + red1[2][t] + red1[3][t];
    const float a2 = red2[0][t] + red2[1][t] + red2[2][t] + red2[3][t];
    sq0[row] = a0 * LOG2E2;               // prescaled: epilogue works in log2 units
    sq1[row] = a1 * LOG2E2;
    align_part[row] = sqrtf(a2);
    S0[row] = 0.0f;
    S1[row] = 0.0f;
  }
}

// Persistent 2-tile row segments; grid (NSEG, 2=view). 4 waves in 2x2, each
// wave 4x4 tiles of mfma_i32_16x16x64_i8 over 4 K=64 chunks per tile. A panel
// staged once; B fragments stream global->VGPR with 1-chunk prefetch. No
// barriers inside or between tiles.
__global__ __launch_bounds__(256) void entropy_tile(
    const unsigned char* __restrict__ ph0, const unsigned char* __restrict__ ph1,
    const float* __restrict__ sq0, const float* __restrict__ sq1,
    float* __restrict__ S0, float* __restrict__ S1) {
  const unsigned char* __restrict__ ph = blockIdx.y ? ph1 : ph0;
  const float* __restrict__ sq = blockIdx.y ? sq1 : sq0;
  float* __restrict__ S        = blockIdx.y ? S1 : S0;

  // decode segment -> (bi, q): row bi has ceil((64-bi)/2) segments;
  // prefix P(bi) = NSEG - G(64-bi).
  const int lin = blockIdx.x;
  int bi = 0;
  while (NSEG - Gfun(64 - (bi + 1)) <= lin) ++bi;
  const int q = lin - (NSEG - Gfun(64 - bi));
  const int bj0 = bi + 2 * q;

  // 32 KB: the A panel (i8, fragment order). Front 17408 B reused as epilogue
  // scratch (guarded by the post-tiles barrier).
  __shared__ __align__(16) char smem[32768];
  float* swp = (float*)smem;

  const int t = threadIdx.x, lane = t & 63, w = t >> 6;
  const int wi = w >> 1, wj = w & 1;
  const int quad = lane >> 4, l15 = lane & 15;
  const int i0 = bi * 128;

  // One-shot A panel stage: 32 x 1KB segments, 8 per wave.
  #pragma unroll
  for (int r8 = 0; r8 < 8; ++r8) {
    const int seg = w * 8 + r8;
    const unsigned char* src = ph + (size_t)bi * 32768 + seg * 1024 + lane * 16;
    load_lds16(src, smem + seg * 1024);
  }
  __syncthreads();   // drains A staging

  const i32x4* __restrict__ phv = (const i32x4*)ph;
  const i32x4* smemv = (const i32x4*)smem;
  const float K2 = 2.0f * LOG2E2 / (S_Q * S_Q);

  float prow[4][4];   // row partial sums, accumulated across both tiles
  #pragma unroll
  for (int m = 0; m < 4; ++m)
    #pragma unroll
    for (int r = 0; r < 4; ++r) prow[m][r] = 0.f;

  auto do_tile = [&](const int bj, const bool diag_t) {
    const int j0 = bj * 128;
    const int baseB = ((bj * 8 + wj * 4) * 4) * 64 + lane;

    float sjl[4];
    #pragma unroll
    for (int n = 0; n < 4; ++n) sjl[n] = sq[j0 + wj * 64 + n * 16 + l15];

    i32x4 bF[2][4];
    #pragma unroll
    for (int n = 0; n < 4; ++n) bF[0][n] = phv[baseB + (n * 4) * 64];

    i32x4 acc[4][4];
    #pragma unroll
    for (int m = 0; m < 4; ++m)
      #pragma unroll
      for (int n = 0; n < 4; ++n) acc[m][n] = (i32x4){0, 0, 0, 0};

    #pragma unroll
    for (int s = 0; s < 4; ++s) {
      const int cur = s & 1, nxt = cur ^ 1;
      if (s < 3) {
        #pragma unroll
        for (int n = 0; n < 4; ++n)
          bF[nxt][n] = phv[baseB + (n * 4 + s + 1) * 64];
      }
      i32x4 ah[4];
      #pragma unroll
      for (int m = 0; m < 4; ++m)
        ah[m] = smemv[(size_t)((wi * 4 + m) * 4 + s) * 64 + lane];
      #pragma unroll
      for (int m = 0; m < 4; ++m)
        #pragma unroll
        for (int n = 0; n < 4; ++n)
          acc[m][n] = __builtin_amdgcn_mfma_i32_16x16x64_i8(ah[m], bF[cur][n], acc[m][n], 0, 0, 0);
      // no barrier: A panel read-only, B private
    }

    // epilogue-lite: accumulate into prow (registers) + per-tile column sums.
    // C/D layout: col = l15, row = quad*4+reg. No fmax (off-diag d2 >= ~260;
    // diag NaN masked after exp).
    float csum[4] = {0.f, 0.f, 0.f, 0.f};
    #pragma unroll
    for (int m = 0; m < 4; ++m) {
      #pragma unroll
      for (int r = 0; r < 4; ++r) {
        const int rowl = m * 16 + quad * 4 + r;
        const int gi = i0 + wi * 64 + rowl;
        const float si = sq[gi];
        float p = 0.f;
        #pragma unroll
        for (int n = 0; n < 4; ++n) {
          const float d2 = fmaf(-K2, (float)acc[m][n][r], si + sjl[n]);
          float e = __builtin_amdgcn_exp2f(-__builtin_amdgcn_sqrtf(d2));
          if (diag_t && gi == j0 + wj * 64 + n * 16 + l15) e = 0.f;  // diag mask
          p += e;
          csum[n] += e;
        }
        prow[m][r] += p;
      }
    }
    if (!diag_t) {
      // column sums -> symmetric contribution S[j] += sum_i exp(-d_ij)
      #pragma unroll
      for (int n = 0; n < 4; ++n) {
        float c2 = csum[n];
        c2 += __shfl_xor(c2, 16, 64);
        c2 += __shfl_xor(c2, 32, 64);
        if (quad == 0) atomicAdd(&S[j0 + wj * 64 + n * 16 + l15], c2);
      }
    }
  };

  if (bj0 == bi) do_tile(bi, true); else do_tile(bj0, false);
  if (bj0 + 1 < NB) do_tile(bj0 + 1, false);

  __syncthreads();   // all waves done reading A before scratch reuse

  // Row reduction: LDS transpose of prow, one atomic set per block.
  const int wbase = w * 1088;  // 64 rows x 17 floats per wave
  #pragma unroll
  for (int m = 0; m < 4; ++m)
    #pragma unroll
    for (int r = 0; r < 4; ++r)
      swp[wbase + (m * 16 + quad * 4 + r) * 17 + l15] = prow[m][r];
  float rs = 0.f;
  #pragma unroll
  for (int j = 0; j < 16; ++j) rs += swp[wbase + lane * 17 + j];
  atomicAdd(&S[i0 + wi * 64 + lane], rs);
}

// Single finalize: 32 blocks x 256 threads, one row each. Block partials go
// to fp32 atomic accumulators; last block (ticket) combines and writes out.
// No device fence: all cross-block traffic is L2-coherence-point atomics.
__global__ __launch_bounds__(256) void finalize_ticket(
    const float* __restrict__ S0, const float* __restrict__ S1,
    const float* __restrict__ align_part,
    float* __restrict__ acc, int* __restrict__ cnt,
    float* __restrict__ out, int n) {
  __shared__ float shl[4], sha[4];
  __shared__ int isLast;
  const int t = threadIdx.x, lane = t & 63, w = t >> 6;
  const int idx = blockIdx.x * 256 + t;
  float lg = __logf(S0[idx]) + __logf(S1[idx]);
  float al = align_part[idx];
  #pragma unroll
  for (int o = 1; o < 64; o <<= 1) {
    lg += __shfl_xor(lg, o, 64);
    al += __shfl_xor(al, o, 64);
  }
  if (lane == 0) { shl[w] = lg; sha[w] = al; }
  __syncthreads();
  if (t == 0) {
    atomicAdd(&acc[0], shl[0] + shl[1] + shl[2] + shl[3]);
    atomicAdd(&acc[1], sha[0] + sha[1] + sha[2] + sha[3]);
    // ensure our accumulator adds hit the coherence point before the ticket
    __asm__ __volatile__("s_waitcnt vmcnt(0)" ::: "memory");
    isLast = (atomicAdd(cnt, 1) == (int)gridDim.x - 1);
  }
  __syncthreads();
  if (t == 0 && isLast) {
    // returning atomics read at the coherence point (no stale lines)
    const float lgs = atomicAdd(&acc[0], 0.0f);
    const float als = atomicAdd(&acc[1], 0.0f);
    const double align = (double)als / (double)n;
    const double entropy = 0.5 * (double)lgs / (double)n - log((double)(n - 1));
    out[0] = (float)(align + entropy);
  }
}

extern "C" void kernel_launch(void* const* d_in, const int* in_sizes, int n_in,
                              void* d_out, int out_size, void* d_ws, size_t ws_size,
                              hipStream_t stream) {
  const float* v0 = (const float*)d_in[0];
  const float* v1 = (const float*)d_in[1];
  float* out = (float*)d_out;
  const int n = in_sizes[0] / D_DIM;  // 8192

  float* ws         = (float*)d_ws;
  float* sq0        = ws;             // n f32 (prescaled by log2e^2)
  float* sq1        = ws + n;
  float* S0         = ws + 2 * n;
  float* S1         = ws + 3 * n;
  float* align_part = ws + 4 * n;
  float* acc        = ws + 5 * n;     // 2 f32 accumulators
  int*   cnt        = (int*)(ws + 5 * n + 2);
  // packed i8 planes, 16B-aligned (5n+64 floats from base)
  unsigned char* ph0 = (unsigned char*)(ws + 5 * n + 64);  // n*256 i8 = 2 MB
  unsigned char* ph1 = ph0 + (size_t)n * D_DIM;            // 2 MB

  prep<<<n / 16, 256, 0, stream>>>(v0, v1, ph0, ph1, sq0, sq1, S0, S1,
                                   align_part, acc, cnt);

  dim3 grid(NSEG, 2);
  entropy_tile<<<grid, 256, 0, stream>>>(ph0, ph1, sq0, sq1, S0, S1);

  finalize_ticket<<<n / 256, 256, 0, stream>>>(S0, S1, align_part, acc, cnt, out, n);
}